// Round 19
// baseline (209.394 us; speedup 1.0000x reference)
//
#include <hip/hip_runtime.h>
#include <hip/hip_bf16.h>

// SNN: B=2048, NI=1024, NH=2048, NO=10, T=128, BETA=0.95, THR=1.0
// r19: split architecture. K1 gemm (frozen) -> A spikegen (pure VALU, bits
// to global, 48-reg state, no LDS/barriers) -> B snn_out (MFMA + scan).
// Fallback to r15 fused kernel if ws_size < cur1+bits.

#define B_   2048
#define NI_  1024
#define NH_  2048
#define NO_  10
#define T_   128

typedef __attribute__((ext_vector_type(8))) short short8;
typedef __attribute__((ext_vector_type(4))) float f32x4;
typedef __attribute__((ext_vector_type(4))) unsigned int u32x4;

__device__ __forceinline__ unsigned int bf16_rne(float f) {
  unsigned int u = __float_as_uint(f);
  return (u + 0x7FFFu + ((u >> 16) & 1u)) >> 16;
}

// ---------------- Kernel 1: cur1 = x @ w1^T + b1 (bf16x3 MFMA, frozen) -----
#define G_ASTRIDE 144
#define G_AOFF    0
#define G_BOFF    (128 * G_ASTRIDE)
#define G_SMEM    (2 * 128 * G_ASTRIDE)

__global__ __launch_bounds__(512, 2) void gemm_cur1(
    const float* __restrict__ x, const float* __restrict__ w1,
    const float* __restrict__ b1, float* __restrict__ cur1) {
  __shared__ __align__(16) char smem[G_SMEM];
  const int tid = threadIdx.x;
  const int lane = tid & 63;
  const int wv = tid >> 6;
  const int wm = wv >> 2;
  const int wn = wv & 3;
  const int n15 = lane & 15;
  const int g = lane >> 4;
  const int brow = blockIdx.y * 128;
  const int bcol = blockIdx.x * 128;
  const int r_st = tid >> 3;
  const int kq = tid & 7;

  f32x4 acc[4][2];
#pragma unroll
  for (int tm = 0; tm < 4; ++tm)
#pragma unroll
    for (int tn = 0; tn < 2; ++tn) acc[tm][tn] = f32x4{0, 0, 0, 0};

  for (int kt = 0; kt < NI_; kt += 32) {
#pragma unroll
    for (int p = 0; p < 2; ++p) {
      const int r = r_st + p * 64;
      const float4 va = *reinterpret_cast<const float4*>(
          &x[(size_t)(brow + r) * NI_ + kt + kq * 4]);
      const float4 vb = *reinterpret_cast<const float4*>(
          &w1[(size_t)(bcol + r) * NI_ + kt + kq * 4]);
      const float fa[4] = {va.x, va.y, va.z, va.w};
      const float fb[4] = {vb.x, vb.y, vb.z, vb.w};
      unsigned ha[4], la[4], hb[4], lb[4];
#pragma unroll
      for (int c = 0; c < 4; ++c) {
        ha[c] = bf16_rne(fa[c]);
        la[c] = bf16_rne(fa[c] - __uint_as_float(ha[c] << 16));
        hb[c] = bf16_rne(fb[c]);
        lb[c] = bf16_rne(fb[c] - __uint_as_float(hb[c] << 16));
      }
      char* arow = smem + G_AOFF + r * G_ASTRIDE;
      char* brw  = smem + G_BOFF + r * G_ASTRIDE;
      *reinterpret_cast<uint2*>(arow + kq * 8) =
          uint2{ha[0] | (ha[1] << 16), ha[2] | (ha[3] << 16)};
      *reinterpret_cast<uint2*>(arow + 64 + kq * 8) =
          uint2{la[0] | (la[1] << 16), la[2] | (la[3] << 16)};
      *reinterpret_cast<uint2*>(brw + kq * 8) =
          uint2{hb[0] | (hb[1] << 16), hb[2] | (hb[3] << 16)};
      *reinterpret_cast<uint2*>(brw + 64 + kq * 8) =
          uint2{lb[0] | (lb[1] << 16), lb[2] | (lb[3] << 16)};
    }
    __syncthreads();

    short8 ah[4], al[4], bh2[2], bl2[2];
#pragma unroll
    for (int tm = 0; tm < 4; ++tm) {
      const char* p = smem + G_AOFF + (wm * 64 + tm * 16 + n15) * G_ASTRIDE;
      ah[tm] = *reinterpret_cast<const short8*>(p + g * 16);
      al[tm] = *reinterpret_cast<const short8*>(p + 64 + g * 16);
    }
#pragma unroll
    for (int tn = 0; tn < 2; ++tn) {
      const char* p = smem + G_BOFF + (wn * 32 + tn * 16 + n15) * G_ASTRIDE;
      bh2[tn] = *reinterpret_cast<const short8*>(p + g * 16);
      bl2[tn] = *reinterpret_cast<const short8*>(p + 64 + g * 16);
    }
#pragma unroll
    for (int tm = 0; tm < 4; ++tm)
#pragma unroll
      for (int tn = 0; tn < 2; ++tn) {
        acc[tm][tn] = __builtin_amdgcn_mfma_f32_16x16x32_bf16(
            ah[tm], bh2[tn], acc[tm][tn], 0, 0, 0);
        acc[tm][tn] = __builtin_amdgcn_mfma_f32_16x16x32_bf16(
            ah[tm], bl2[tn], acc[tm][tn], 0, 0, 0);
        acc[tm][tn] = __builtin_amdgcn_mfma_f32_16x16x32_bf16(
            al[tm], bh2[tn], acc[tm][tn], 0, 0, 0);
      }
    __syncthreads();
  }

#pragma unroll
  for (int tn = 0; tn < 2; ++tn) {
    const int col = bcol + wn * 32 + tn * 16 + n15;
    const float bias = b1[col];
#pragma unroll
    for (int tm = 0; tm < 4; ++tm) {
      const int rowb = brow + wm * 64 + tm * 16 + g * 4;
#pragma unroll
      for (int r = 0; r < 4; ++r)
        cur1[(size_t)(rowb + r) * NH_ + col] = acc[tm][tn][r] + bias;
    }
  }
}

// ---------------- Kernel A: spikegen — layer-1 LIF -> bit-packed global -----
// 256 threads = 4 waves = 2 batches (w>>1 = local batch, hf = w&1).
// Lane owns neurons hf*1024 + lane*16 + i. Halfword index hf*64+lane of the
// (b,t) 64-word row => word k covers neurons 32k..32k+31 (r11-verified).
__global__ __launch_bounds__(256, 4) void spikegen(
    const float* __restrict__ cur1, unsigned short* __restrict__ bits16) {
  const int lane = threadIdx.x & 63;
  const int w = threadIdx.x >> 6;
  const int bq = w >> 1;
  const int hf = w & 1;
  const int bb = blockIdx.x * 2 + bq;

  float mem1[16], c1v[16], spk[16];
  {
    const float* base = cur1 + (size_t)bb * NH_ + hf * 1024 + lane * 16;
#pragma unroll
    for (int q = 0; q < 4; ++q) {
      const float4 v = *reinterpret_cast<const float4*>(base + q * 4);
      c1v[q * 4 + 0] = v.x; c1v[q * 4 + 1] = v.y;
      c1v[q * 4 + 2] = v.z; c1v[q * 4 + 3] = v.w;
    }
#pragma unroll
    for (int i = 0; i < 16; ++i) { mem1[i] = 0.0f; spk[i] = 0.0f; }
  }

  unsigned short* dst = bits16 + (size_t)bb * T_ * 128 + hf * 64 + lane;
  for (int t = 0; t < T_; ++t) {
    unsigned W = 0;
#pragma unroll
    for (int i = 15; i >= 0; --i) {
      const float m = fmaf(0.95f, mem1[i], c1v[i] - spk[i]);
      mem1[i] = m;
      const bool c = m > 1.0f;
      W = W + W + (c ? 1u : 0u);
      spk[i] = c ? 1.0f : 0.0f;
    }
    dst[t * 128] = (unsigned short)W;
  }
}

// ---------------- Kernel B: snn_out — MFMA layer-2 + mem2 scan --------------
// 512 threads = 8 waves, 256 blocks (8 batches each). Per chunk (TC=16):
// stage bits global->LDS (rows padded to 68 words, 16B-aligned) -> P2 MFMA
// (wave w: kb=w*8+kbl, single-bf16 w2) -> comb -> scan (waves 0-7, lanes<10).
#define BB_TC 16
#define BB_LUT_OFF  0
#define BB_BITS_OFF 128
#define BB_COMB_OFF (128 + 34816)   // 34944
#define BB_SMEM     (34944 + 40960) // 75904

__global__ __launch_bounds__(512, 2) void snn_out(
    const unsigned* __restrict__ bitsg, const float* __restrict__ w2,
    const float* __restrict__ b2, float* __restrict__ spk2_rec,
    float* __restrict__ mem2_rec) {
  extern __shared__ char smem[];
  uint2* lutw = reinterpret_cast<uint2*>(smem + BB_LUT_OFF);
  const uint2* lut = lutw;
  unsigned* bitsl = reinterpret_cast<unsigned*>(smem + BB_BITS_OFF);
  float* comb = reinterpret_cast<float*>(smem + BB_COMB_OFF);
  const int tid = threadIdx.x;
  const int lane = tid & 63;
  const int w = tid >> 6;
  const int bbase = blockIdx.x * 8;

  if (tid < 16) {
    lutw[tid] = uint2{(tid & 1 ? 0x3F80u : 0u) | (tid & 2 ? 0x3F800000u : 0u),
                      (tid & 4 ? 0x3F80u : 0u) | (tid & 8 ? 0x3F800000u : 0u)};
  }

  // w2 B-fragments, single bf16; kb = w*8 + kbl (verified map)
  u32x4 bhi[8];
  {
    const int o = lane & 15;
    const int koff = (lane >> 4) * 8;
#pragma unroll
    for (int kbl = 0; kbl < 8; ++kbl) {
      const int kb = w * 8 + kbl;
      unsigned int hw[4];
#pragma unroll
      for (int p = 0; p < 4; ++p) {
        unsigned int h0 = 0, h1 = 0;
        if (o < NO_) {
          const int k = kb * 32 + koff + p * 2;
          h0 = bf16_rne(w2[(size_t)o * NH_ + k]);
          h1 = bf16_rne(w2[(size_t)o * NH_ + k + 1]);
        }
        hw[p] = h0 | (h1 << 16);
      }
      bhi[kbl] = u32x4{hw[0], hw[1], hw[2], hw[3]};
    }
  }

  float mem2 = 0.0f, spk2 = 0.0f, b2v = 0.0f;
  float *srec = nullptr, *mrec = nullptr;
  if (lane < NO_) {
    b2v = b2[lane];
    srec = spk2_rec + (size_t)(bbase + w) * NO_ + lane;
    mrec = mem2_rec + (size_t)(bbase + w) * NO_ + lane;
  }

  const int n15 = lane & 15;
  const int g = lane >> 4;
  const unsigned char* bytes = reinterpret_cast<const unsigned char*>(bitsl);

  for (int ch = 0; ch < T_ / BB_TC; ++ch) {
    // ---- stage bits chunk: 8192 words, uint4 per thread x4 ----
#pragma unroll
    for (int j = 0; j < 4; ++j) {
      const int q = tid + j * 512;       // quad index 0..2047
      const int row = q >> 4;            // 0..127 = b*16+tl
      const int kq = q & 15;
      const int b = row >> 4, tl = row & 15;
      const uint4 v = *reinterpret_cast<const uint4*>(
          bitsg + ((size_t)(bbase + b) * T_ + ch * BB_TC + tl) * 64 + kq * 4);
      *reinterpret_cast<uint4*>(bitsl + row * 68 + kq * 4) = v;
    }
    __syncthreads();

    // ---- P2: MFMA partials ----
    for (int b = 0; b < 8; ++b) {
      const int rbase = ((b * BB_TC + n15) * 68 + w * 8) * 4 + g;
      f32x4 acc = {0.0f, 0.0f, 0.0f, 0.0f};
#pragma unroll
      for (int kbl = 0; kbl < 8; ++kbl) {
        const unsigned byt = bytes[rbase + kbl * 4];
        const uint2 lo2 = lut[byt & 15u];
        const uint2 hi2 = lut[byt >> 4];
        const u32x4 A = {lo2.x, lo2.y, hi2.x, hi2.y};
        const short8 af = __builtin_bit_cast(short8, A);
        acc = __builtin_amdgcn_mfma_f32_16x16x32_bf16(
            af, __builtin_bit_cast(short8, bhi[kbl]), acc, 0, 0, 0);
      }
      if (n15 < NO_)
        *reinterpret_cast<f32x4*>(
            &comb[w * 1280 + b * 160 + g * 40 + n15 * 4]) = acc;
    }
    __syncthreads();

    // ---- scan: batch w, lanes < NO_ ----
    if (lane < NO_) {
      const float* cbase = comb + w * 160 + lane * 4;
#pragma unroll
      for (int tl = 0; tl < BB_TC; ++tl) {
        const int off = (tl >> 2) * 40 + (tl & 3);
        float s = 0.0f;
#pragma unroll
        for (int kk = 0; kk < 8; ++kk) s += cbase[kk * 1280 + off];
        const float cur2 = s + b2v;
        float m = fmaf(0.95f, mem2, cur2);
        m = m - spk2;
        mem2 = m;
        spk2 = (m > 1.0f) ? 1.0f : 0.0f;
        const int t = ch * BB_TC + tl;
        srec[(size_t)t * (B_ * NO_)] = spk2;
        mrec[(size_t)t * (B_ * NO_)] = m;
      }
    }
    // staging(ch+1) overwrites bits only after all waves pass the next
    // barrier-less region: bits reads finished before bar2; comb overwrite
    // happens after bar1(ch+1), scan reads finish before it.
  }
}

// ---------------- Fallback: r15 fused kernel (ws too small for bits) --------
#define FB_TC 16
#define FB_NCH (T_ / FB_TC)
#define FB_LUT_OFF  0
#define FB_BITS_OFF 128
#define FB_BITS_PAR 8320
#define FB_COMB_OFF 66688
#define FB_COMB_PAR 10240
#define FB_SMEM 148608

__global__ __launch_bounds__(512, 2) void snn_fused(
    const float* __restrict__ cur1, const float* __restrict__ w2,
    const float* __restrict__ b2, float* __restrict__ spk2_rec,
    float* __restrict__ mem2_rec) {
  extern __shared__ char smem[];
  uint2* lutw = reinterpret_cast<uint2*>(smem + FB_LUT_OFF);
  const uint2* lut = lutw;
  unsigned* bits = reinterpret_cast<unsigned*>(smem + FB_BITS_OFF);
  float* comb = reinterpret_cast<float*>(smem + FB_COMB_OFF);
  const int tid = threadIdx.x;
  const int lane = tid & 63;
  const int w = tid >> 6;
  const int bbase = blockIdx.x * 8;
  const int bb = bbase + w;

  if (tid < 16) {
    lutw[tid] = uint2{(tid & 1 ? 0x3F80u : 0u) | (tid & 2 ? 0x3F800000u : 0u),
                      (tid & 4 ? 0x3F80u : 0u) | (tid & 8 ? 0x3F800000u : 0u)};
  }

  float mem1[32], c1v[32], c1m[32], cc[32];
  {
    const float* base = cur1 + (size_t)bb * NH_ + lane * 32;
#pragma unroll
    for (int q = 0; q < 8; ++q) {
      const float4 v = *reinterpret_cast<const float4*>(base + q * 4);
      c1v[q * 4 + 0] = v.x; c1v[q * 4 + 1] = v.y;
      c1v[q * 4 + 2] = v.z; c1v[q * 4 + 3] = v.w;
    }
#pragma unroll
    for (int i = 0; i < 32; ++i) {
      mem1[i] = 0.0f;
      c1m[i] = c1v[i] - 1.0f;
      cc[i] = c1v[i];
    }
  }

  u32x4 bhi[8], blo[8];
  {
    const int o = lane & 15;
    const int koff = (lane >> 4) * 8;
#pragma unroll
    for (int kbl = 0; kbl < 8; ++kbl) {
      const int kb = w * 8 + kbl;
      unsigned int hw[4], lw[4];
#pragma unroll
      for (int p = 0; p < 4; ++p) {
        unsigned int h0 = 0, h1 = 0, l0 = 0, l1 = 0;
        if (o < NO_) {
          const int k = kb * 32 + koff + p * 2;
          const float f0 = w2[(size_t)o * NH_ + k];
          const float f1 = w2[(size_t)o * NH_ + k + 1];
          h0 = bf16_rne(f0); h1 = bf16_rne(f1);
          l0 = bf16_rne(f0 - __uint_as_float(h0 << 16));
          l1 = bf16_rne(f1 - __uint_as_float(h1 << 16));
        }
        hw[p] = h0 | (h1 << 16);
        lw[p] = l0 | (l1 << 16);
      }
      bhi[kbl] = u32x4{hw[0], hw[1], hw[2], hw[3]};
      blo[kbl] = u32x4{lw[0], lw[1], lw[2], lw[3]};
    }
  }

  float mem2 = 0.0f, spk2 = 0.0f, b2v = 0.0f;
  float *srec = nullptr, *mrec = nullptr;
  if (lane < NO_) {
    b2v = b2[lane];
    srec = spk2_rec + (size_t)bb * NO_ + lane;
    mrec = mem2_rec + (size_t)bb * NO_ + lane;
  }

  const int n15 = lane & 15;
  const int g = lane >> 4;
  const unsigned char* bytes = reinterpret_cast<const unsigned char*>(smem);

  auto P1_STEP = [&](unsigned* bitsP, int tl) {
    unsigned W = 0;
#pragma unroll
    for (int i = 31; i >= 0; --i) {
      const float m = fmaf(0.95f, mem1[i], cc[i]);
      mem1[i] = m;
      const bool c = m > 1.0f;
      W = W + W + (c ? 1u : 0u);
      cc[i] = c ? c1m[i] : c1v[i];
    }
    bitsP[(w * FB_TC + tl) * 65 + lane] = W;
  };

  for (int tl = 0; tl < FB_TC; ++tl) P1_STEP(bits, tl);
  __syncthreads();

  for (int ch = 0; ch < FB_NCH; ++ch) {
    const int cur = ch & 1;
    unsigned* bitsN = bits + (cur ^ 1) * FB_BITS_PAR;
    float* combC = comb + cur * FB_COMB_PAR;
    const float* combV = comb + (cur ^ 1) * FB_COMB_PAR;
    const int bbyte = FB_BITS_OFF + cur * (FB_BITS_PAR * 4);

    if (ch > 0 && lane < NO_) {
      const float* cbase = combV + w * 160 + lane * 4;
#pragma unroll
      for (int tl = 0; tl < FB_TC; ++tl) {
        const int off = (tl >> 2) * 40 + (tl & 3);
        float s = 0.0f;
#pragma unroll
        for (int ww = 0; ww < 8; ++ww) s += cbase[ww * 1280 + off];
        const float cur2 = s + b2v;
        float m = fmaf(0.95f, mem2, cur2);
        m = m - spk2;
        mem2 = m;
        spk2 = (m > 1.0f) ? 1.0f : 0.0f;
        const int t = (ch - 1) * FB_TC + tl;
        srec[(size_t)t * (B_ * NO_)] = spk2;
        mrec[(size_t)t * (B_ * NO_)] = m;
      }
    }

#pragma unroll
    for (int b = 0; b < 8; ++b) {
      const int rbase = bbyte + ((b * FB_TC + n15) * 65 + w * 8) * 4 + g;
      f32x4 acc = {0.0f, 0.0f, 0.0f, 0.0f};
#pragma unroll
      for (int kbl = 0; kbl < 8; ++kbl) {
        const unsigned byt = bytes[rbase + kbl * 4];
        const uint2 lo2 = lut[byt & 15u];
        const uint2 hi2 = lut[byt >> 4];
        const u32x4 A = {lo2.x, lo2.y, hi2.x, hi2.y};
        const short8 af = __builtin_bit_cast(short8, A);
        acc = __builtin_amdgcn_mfma_f32_16x16x32_bf16(
            af, __builtin_bit_cast(short8, bhi[kbl]), acc, 0, 0, 0);
        acc = __builtin_amdgcn_mfma_f32_16x16x32_bf16(
            af, __builtin_bit_cast(short8, blo[kbl]), acc, 0, 0, 0);
      }
      if (n15 < NO_)
        *reinterpret_cast<f32x4*>(
            &combC[w * 1280 + b * 160 + g * 40 + n15 * 4]) = acc;
      if (ch < FB_NCH - 1) {
        P1_STEP(bitsN, 2 * b);
        P1_STEP(bitsN, 2 * b + 1);
      }
    }

    __syncthreads();
  }

  if (lane < NO_) {
    const float* cbase =
        comb + ((FB_NCH - 1) & 1) * FB_COMB_PAR + w * 160 + lane * 4;
#pragma unroll
    for (int tl = 0; tl < FB_TC; ++tl) {
      const int off = (tl >> 2) * 40 + (tl & 3);
      float s = 0.0f;
#pragma unroll
      for (int ww = 0; ww < 8; ++ww) s += cbase[ww * 1280 + off];
      const float cur2 = s + b2v;
      float m = fmaf(0.95f, mem2, cur2);
      m = m - spk2;
      mem2 = m;
      spk2 = (m > 1.0f) ? 1.0f : 0.0f;
      const int t = (FB_NCH - 1) * FB_TC + tl;
      srec[(size_t)t * (B_ * NO_)] = spk2;
      mrec[(size_t)t * (B_ * NO_)] = m;
    }
  }
}

// ---------------------------------------------------------------------------
#define CUR1_BYTES ((size_t)B_ * NH_ * 4)            // 16 MB
#define BITS_BYTES ((size_t)B_ * T_ * 64 * 4)        // 67 MB
#define WS_NEED (CUR1_BYTES + BITS_BYTES)

extern "C" void kernel_launch(void* const* d_in, const int* in_sizes, int n_in,
                              void* d_out, int out_size, void* d_ws, size_t ws_size,
                              hipStream_t stream) {
  const float* x  = (const float*)d_in[0];
  const float* w1 = (const float*)d_in[1];
  const float* b1 = (const float*)d_in[2];
  const float* w2 = (const float*)d_in[3];
  const float* b2 = (const float*)d_in[4];
  float* out = (float*)d_out;
  float* cur1 = (float*)d_ws;

  float* spk2_rec = out;
  float* mem2_rec = out + (size_t)T_ * B_ * NO_;

  dim3 g1(NH_ / 128, B_ / 128);
  gemm_cur1<<<g1, 512, 0, stream>>>(x, w1, b1, cur1);

  if (ws_size >= WS_NEED) {
    unsigned* bitsg = (unsigned*)((char*)d_ws + CUR1_BYTES);
    (void)hipFuncSetAttribute(reinterpret_cast<const void*>(snn_out),
                              hipFuncAttributeMaxDynamicSharedMemorySize,
                              BB_SMEM);
    spikegen<<<B_ / 2, 256, 0, stream>>>(cur1, (unsigned short*)bitsg);
    snn_out<<<B_ / 8, 512, BB_SMEM, stream>>>(bitsg, w2, b2, spk2_rec,
                                              mem2_rec);
  } else {
    (void)hipFuncSetAttribute(reinterpret_cast<const void*>(snn_fused),
                              hipFuncAttributeMaxDynamicSharedMemorySize,
                              FB_SMEM);
    snn_fused<<<B_ / 8, 512, FB_SMEM, stream>>>(cur1, w2, b2, spk2_rec,
                                                mem2_rec);
  }
}

// Round 20
// 192.847 us; speedup vs baseline: 1.0858x; 1.0858x over previous
//
#include <hip/hip_runtime.h>
#include <hip/hip_bf16.h>

// SNN: B=2048, NI=1024, NH=2048, NO=10, T=128, BETA=0.95, THR=1.0
// r20: split architecture, spill-free. K1 gemm (frozen) -> A spikegen
// (512thr/(512,2): 4-inst LIF, halfword bits to global) -> B snn_out
// (4 batches/block, STATIC 38KB LDS, MFMA + scan). Fallback r15-fused.

#define B_   2048
#define NI_  1024
#define NH_  2048
#define NO_  10
#define T_   128

typedef __attribute__((ext_vector_type(8))) short short8;
typedef __attribute__((ext_vector_type(4))) float f32x4;
typedef __attribute__((ext_vector_type(4))) unsigned int u32x4;

__device__ __forceinline__ unsigned int bf16_rne(float f) {
  unsigned int u = __float_as_uint(f);
  return (u + 0x7FFFu + ((u >> 16) & 1u)) >> 16;
}

// ---------------- Kernel 1: cur1 = x @ w1^T + b1 (bf16x3 MFMA, frozen) -----
#define G_ASTRIDE 144
#define G_AOFF    0
#define G_BOFF    (128 * G_ASTRIDE)
#define G_SMEM    (2 * 128 * G_ASTRIDE)

__global__ __launch_bounds__(512, 2) void gemm_cur1(
    const float* __restrict__ x, const float* __restrict__ w1,
    const float* __restrict__ b1, float* __restrict__ cur1) {
  __shared__ __align__(16) char smem[G_SMEM];
  const int tid = threadIdx.x;
  const int lane = tid & 63;
  const int wv = tid >> 6;
  const int wm = wv >> 2;
  const int wn = wv & 3;
  const int n15 = lane & 15;
  const int g = lane >> 4;
  const int brow = blockIdx.y * 128;
  const int bcol = blockIdx.x * 128;
  const int r_st = tid >> 3;
  const int kq = tid & 7;

  f32x4 acc[4][2];
#pragma unroll
  for (int tm = 0; tm < 4; ++tm)
#pragma unroll
    for (int tn = 0; tn < 2; ++tn) acc[tm][tn] = f32x4{0, 0, 0, 0};

  for (int kt = 0; kt < NI_; kt += 32) {
#pragma unroll
    for (int p = 0; p < 2; ++p) {
      const int r = r_st + p * 64;
      const float4 va = *reinterpret_cast<const float4*>(
          &x[(size_t)(brow + r) * NI_ + kt + kq * 4]);
      const float4 vb = *reinterpret_cast<const float4*>(
          &w1[(size_t)(bcol + r) * NI_ + kt + kq * 4]);
      const float fa[4] = {va.x, va.y, va.z, va.w};
      const float fb[4] = {vb.x, vb.y, vb.z, vb.w};
      unsigned ha[4], la[4], hb[4], lb[4];
#pragma unroll
      for (int c = 0; c < 4; ++c) {
        ha[c] = bf16_rne(fa[c]);
        la[c] = bf16_rne(fa[c] - __uint_as_float(ha[c] << 16));
        hb[c] = bf16_rne(fb[c]);
        lb[c] = bf16_rne(fb[c] - __uint_as_float(hb[c] << 16));
      }
      char* arow = smem + G_AOFF + r * G_ASTRIDE;
      char* brw  = smem + G_BOFF + r * G_ASTRIDE;
      *reinterpret_cast<uint2*>(arow + kq * 8) =
          uint2{ha[0] | (ha[1] << 16), ha[2] | (ha[3] << 16)};
      *reinterpret_cast<uint2*>(arow + 64 + kq * 8) =
          uint2{la[0] | (la[1] << 16), la[2] | (la[3] << 16)};
      *reinterpret_cast<uint2*>(brw + kq * 8) =
          uint2{hb[0] | (hb[1] << 16), hb[2] | (hb[3] << 16)};
      *reinterpret_cast<uint2*>(brw + 64 + kq * 8) =
          uint2{lb[0] | (lb[1] << 16), lb[2] | (lb[3] << 16)};
    }
    __syncthreads();

    short8 ah[4], al[4], bh2[2], bl2[2];
#pragma unroll
    for (int tm = 0; tm < 4; ++tm) {
      const char* p = smem + G_AOFF + (wm * 64 + tm * 16 + n15) * G_ASTRIDE;
      ah[tm] = *reinterpret_cast<const short8*>(p + g * 16);
      al[tm] = *reinterpret_cast<const short8*>(p + 64 + g * 16);
    }
#pragma unroll
    for (int tn = 0; tn < 2; ++tn) {
      const char* p = smem + G_BOFF + (wn * 32 + tn * 16 + n15) * G_ASTRIDE;
      bh2[tn] = *reinterpret_cast<const short8*>(p + g * 16);
      bl2[tn] = *reinterpret_cast<const short8*>(p + 64 + g * 16);
    }
#pragma unroll
    for (int tm = 0; tm < 4; ++tm)
#pragma unroll
      for (int tn = 0; tn < 2; ++tn) {
        acc[tm][tn] = __builtin_amdgcn_mfma_f32_16x16x32_bf16(
            ah[tm], bh2[tn], acc[tm][tn], 0, 0, 0);
        acc[tm][tn] = __builtin_amdgcn_mfma_f32_16x16x32_bf16(
            ah[tm], bl2[tn], acc[tm][tn], 0, 0, 0);
        acc[tm][tn] = __builtin_amdgcn_mfma_f32_16x16x32_bf16(
            al[tm], bh2[tn], acc[tm][tn], 0, 0, 0);
      }
    __syncthreads();
  }

#pragma unroll
  for (int tn = 0; tn < 2; ++tn) {
    const int col = bcol + wn * 32 + tn * 16 + n15;
    const float bias = b1[col];
#pragma unroll
    for (int tm = 0; tm < 4; ++tm) {
      const int rowb = brow + wm * 64 + tm * 16 + g * 4;
#pragma unroll
      for (int r = 0; r < 4; ++r)
        cur1[(size_t)(rowb + r) * NH_ + col] = acc[tm][tn][r] + bias;
    }
  }
}

// ---------------- Kernel A: spikegen — layer-1 LIF -> bit-packed global -----
// 512 threads = 8 waves = 4 batches (bq=w>>1, hf=w&1); 16 neurons/lane.
// Halfword hw = hf*64+lane of (b,t) 128-hw row covers neurons 16hw..16hw+15
// => word k covers 32k..32k+31 (r19-verified layout, unchanged).
__global__ __launch_bounds__(512, 2) void spikegen(
    const float* __restrict__ cur1, unsigned short* __restrict__ bits16) {
  const int lane = threadIdx.x & 63;
  const int w = threadIdx.x >> 6;
  const int bq = w >> 1;
  const int hf = w & 1;
  const int bb = blockIdx.x * 4 + bq;

  float mem1[16], c1v[16], c1m[16], cc[16];
  {
    const float* base = cur1 + (size_t)bb * NH_ + hf * 1024 + lane * 16;
#pragma unroll
    for (int q = 0; q < 4; ++q) {
      const float4 v = *reinterpret_cast<const float4*>(base + q * 4);
      c1v[q * 4 + 0] = v.x; c1v[q * 4 + 1] = v.y;
      c1v[q * 4 + 2] = v.z; c1v[q * 4 + 3] = v.w;
    }
#pragma unroll
    for (int i = 0; i < 16; ++i) {
      mem1[i] = 0.0f;
      c1m[i] = c1v[i] - 1.0f;
      cc[i] = c1v[i];
    }
  }

  unsigned short* dst = bits16 + (size_t)bb * T_ * 128 + hf * 64 + lane;
  for (int t = 0; t < T_; ++t) {
    unsigned W = 0;
#pragma unroll
    for (int i = 15; i >= 0; --i) {
      const float m = fmaf(0.95f, mem1[i], cc[i]);
      mem1[i] = m;
      const bool c = m > 1.0f;
      W = W + W + (c ? 1u : 0u);
      cc[i] = c ? c1m[i] : c1v[i];
    }
    dst[t * 128] = (unsigned short)W;
  }
}

// ---------------- Kernel B: snn_out — MFMA layer-2 + mem2 scan --------------
// 512 threads = 8 waves, 512 blocks (4 batches each). STATIC 38KB LDS.
// Per chunk (TC=16): stage bits global->LDS (68-word rows) -> P2 MFMA
// (wave w: kb=w*8+kbl, single-bf16 w2) -> comb -> scan (waves 0-3, lanes<10).
#define SO_TC 16

__global__ __launch_bounds__(512, 2) void snn_out(
    const unsigned* __restrict__ bitsg, const float* __restrict__ w2,
    const float* __restrict__ b2, float* __restrict__ spk2_rec,
    float* __restrict__ mem2_rec) {
  __shared__ uint2 lut[16];
  __shared__ __align__(16) unsigned bitsl[64 * 68];   // 17408 B
  __shared__ __align__(16) float comb[8 * 640];       // 20480 B
  const int tid = threadIdx.x;
  const int lane = tid & 63;
  const int w = tid >> 6;
  const int bbase = blockIdx.x * 4;

  if (tid < 16) {
    lut[tid] = uint2{(tid & 1 ? 0x3F80u : 0u) | (tid & 2 ? 0x3F800000u : 0u),
                     (tid & 4 ? 0x3F80u : 0u) | (tid & 8 ? 0x3F800000u : 0u)};
  }

  // w2 B-fragments, single bf16; kb = w*8 + kbl (verified map)
  u32x4 bhi[8];
  {
    const int o = lane & 15;
    const int koff = (lane >> 4) * 8;
#pragma unroll
    for (int kbl = 0; kbl < 8; ++kbl) {
      const int kb = w * 8 + kbl;
      unsigned int hw[4];
#pragma unroll
      for (int p = 0; p < 4; ++p) {
        unsigned int h0 = 0, h1 = 0;
        if (o < NO_) {
          const int k = kb * 32 + koff + p * 2;
          h0 = bf16_rne(w2[(size_t)o * NH_ + k]);
          h1 = bf16_rne(w2[(size_t)o * NH_ + k + 1]);
        }
        hw[p] = h0 | (h1 << 16);
      }
      bhi[kbl] = u32x4{hw[0], hw[1], hw[2], hw[3]};
    }
  }

  float mem2 = 0.0f, spk2 = 0.0f, b2v = 0.0f;
  float *srec = nullptr, *mrec = nullptr;
  if (w < 4 && lane < NO_) {
    b2v = b2[lane];
    srec = spk2_rec + (size_t)(bbase + w) * NO_ + lane;
    mrec = mem2_rec + (size_t)(bbase + w) * NO_ + lane;
  }

  const int n15 = lane & 15;
  const int g = lane >> 4;
  const unsigned char* bytes = reinterpret_cast<const unsigned char*>(bitsl);

  for (int ch = 0; ch < T_ / SO_TC; ++ch) {
    // ---- stage bits chunk: 64 rows x 64 words; uint4 x2 per thread ----
#pragma unroll
    for (int j = 0; j < 2; ++j) {
      const int q = tid + j * 512;       // quad index 0..1023
      const int row = q >> 4;            // 0..63 = b*16+tl
      const int kq = q & 15;
      const int b = row >> 4, tl = row & 15;
      const uint4 v = *reinterpret_cast<const uint4*>(
          bitsg + ((size_t)(bbase + b) * T_ + ch * SO_TC + tl) * 64 + kq * 4);
      *reinterpret_cast<uint4*>(bitsl + row * 68 + kq * 4) = v;
    }
    __syncthreads();

    // ---- P2: MFMA partials ----
#pragma unroll
    for (int b = 0; b < 4; ++b) {
      const int rbase = ((b * SO_TC + n15) * 68 + w * 8) * 4 + g;
      f32x4 acc = {0.0f, 0.0f, 0.0f, 0.0f};
#pragma unroll
      for (int kbl = 0; kbl < 8; ++kbl) {
        const unsigned byt = bytes[rbase + kbl * 4];
        const uint2 lo2 = lut[byt & 15u];
        const uint2 hi2 = lut[byt >> 4];
        const u32x4 A = {lo2.x, lo2.y, hi2.x, hi2.y};
        const short8 af = __builtin_bit_cast(short8, A);
        acc = __builtin_amdgcn_mfma_f32_16x16x32_bf16(
            af, __builtin_bit_cast(short8, bhi[kbl]), acc, 0, 0, 0);
      }
      if (n15 < NO_)
        *reinterpret_cast<f32x4*>(
            &comb[w * 640 + b * 160 + g * 40 + n15 * 4]) = acc;
    }
    __syncthreads();

    // ---- scan: batch w (waves 0-3), lanes < NO_ ----
    if (w < 4 && lane < NO_) {
      const float* cbase = comb + w * 160 + lane * 4;
#pragma unroll
      for (int tl = 0; tl < SO_TC; ++tl) {
        const int off = (tl >> 2) * 40 + (tl & 3);
        float s = 0.0f;
#pragma unroll
        for (int kk = 0; kk < 8; ++kk) s += cbase[kk * 640 + off];
        const float cur2 = s + b2v;
        float m = fmaf(0.95f, mem2, cur2);
        m = m - spk2;
        mem2 = m;
        spk2 = (m > 1.0f) ? 1.0f : 0.0f;
        const int t = ch * SO_TC + tl;
        srec[(size_t)t * (B_ * NO_)] = spk2;
        mrec[(size_t)t * (B_ * NO_)] = m;
      }
    }
    // stage(ch+1) is after this wave's next barrier-free region: bits reads
    // done before bar2; comb overwrite happens after bar1(ch+1) which scan
    // waves must also pass, so scan reads complete first.
  }
}

// ---------------- Fallback: r15 fused kernel (ws too small for bits) --------
#define FB_TC 16
#define FB_NCH (T_ / FB_TC)
#define FB_LUT_OFF  0
#define FB_BITS_OFF 128
#define FB_BITS_PAR 8320
#define FB_COMB_OFF 66688
#define FB_COMB_PAR 10240
#define FB_SMEM 148608

__global__ __launch_bounds__(512, 2) void snn_fused(
    const float* __restrict__ cur1, const float* __restrict__ w2,
    const float* __restrict__ b2, float* __restrict__ spk2_rec,
    float* __restrict__ mem2_rec) {
  extern __shared__ char smem[];
  uint2* lutw = reinterpret_cast<uint2*>(smem + FB_LUT_OFF);
  const uint2* lut2 = lutw;
  unsigned* bits = reinterpret_cast<unsigned*>(smem + FB_BITS_OFF);
  float* comb = reinterpret_cast<float*>(smem + FB_COMB_OFF);
  const int tid = threadIdx.x;
  const int lane = tid & 63;
  const int w = tid >> 6;
  const int bbase = blockIdx.x * 8;
  const int bb = bbase + w;

  if (tid < 16) {
    lutw[tid] = uint2{(tid & 1 ? 0x3F80u : 0u) | (tid & 2 ? 0x3F800000u : 0u),
                      (tid & 4 ? 0x3F80u : 0u) | (tid & 8 ? 0x3F800000u : 0u)};
  }

  float mem1[32], c1v[32], c1m[32], cc[32];
  {
    const float* base = cur1 + (size_t)bb * NH_ + lane * 32;
#pragma unroll
    for (int q = 0; q < 8; ++q) {
      const float4 v = *reinterpret_cast<const float4*>(base + q * 4);
      c1v[q * 4 + 0] = v.x; c1v[q * 4 + 1] = v.y;
      c1v[q * 4 + 2] = v.z; c1v[q * 4 + 3] = v.w;
    }
#pragma unroll
    for (int i = 0; i < 32; ++i) {
      mem1[i] = 0.0f;
      c1m[i] = c1v[i] - 1.0f;
      cc[i] = c1v[i];
    }
  }

  u32x4 bhi[8], blo[8];
  {
    const int o = lane & 15;
    const int koff = (lane >> 4) * 8;
#pragma unroll
    for (int kbl = 0; kbl < 8; ++kbl) {
      const int kb = w * 8 + kbl;
      unsigned int hw[4], lw[4];
#pragma unroll
      for (int p = 0; p < 4; ++p) {
        unsigned int h0 = 0, h1 = 0, l0 = 0, l1 = 0;
        if (o < NO_) {
          const int k = kb * 32 + koff + p * 2;
          const float f0 = w2[(size_t)o * NH_ + k];
          const float f1 = w2[(size_t)o * NH_ + k + 1];
          h0 = bf16_rne(f0); h1 = bf16_rne(f1);
          l0 = bf16_rne(f0 - __uint_as_float(h0 << 16));
          l1 = bf16_rne(f1 - __uint_as_float(h1 << 16));
        }
        hw[p] = h0 | (h1 << 16);
        lw[p] = l0 | (l1 << 16);
      }
      bhi[kbl] = u32x4{hw[0], hw[1], hw[2], hw[3]};
      blo[kbl] = u32x4{lw[0], lw[1], lw[2], lw[3]};
    }
  }

  float mem2 = 0.0f, spk2 = 0.0f, b2v = 0.0f;
  float *srec = nullptr, *mrec = nullptr;
  if (lane < NO_) {
    b2v = b2[lane];
    srec = spk2_rec + (size_t)bb * NO_ + lane;
    mrec = mem2_rec + (size_t)bb * NO_ + lane;
  }

  const int n15 = lane & 15;
  const int g = lane >> 4;
  const unsigned char* bytes = reinterpret_cast<const unsigned char*>(smem);

  auto P1_STEP = [&](unsigned* bitsP, int tl) {
    unsigned W = 0;
#pragma unroll
    for (int i = 31; i >= 0; --i) {
      const float m = fmaf(0.95f, mem1[i], cc[i]);
      mem1[i] = m;
      const bool c = m > 1.0f;
      W = W + W + (c ? 1u : 0u);
      cc[i] = c ? c1m[i] : c1v[i];
    }
    bitsP[(w * FB_TC + tl) * 65 + lane] = W;
  };

  for (int tl = 0; tl < FB_TC; ++tl) P1_STEP(bits, tl);
  __syncthreads();

  for (int ch = 0; ch < FB_NCH; ++ch) {
    const int cur = ch & 1;
    unsigned* bitsN = bits + (cur ^ 1) * FB_BITS_PAR;
    float* combC = comb + cur * FB_COMB_PAR;
    const float* combV = comb + (cur ^ 1) * FB_COMB_PAR;
    const int bbyte = FB_BITS_OFF + cur * (FB_BITS_PAR * 4);

    if (ch > 0 && lane < NO_) {
      const float* cbase = combV + w * 160 + lane * 4;
#pragma unroll
      for (int tl = 0; tl < FB_TC; ++tl) {
        const int off = (tl >> 2) * 40 + (tl & 3);
        float s = 0.0f;
#pragma unroll
        for (int ww = 0; ww < 8; ++ww) s += cbase[ww * 1280 + off];
        const float cur2 = s + b2v;
        float m = fmaf(0.95f, mem2, cur2);
        m = m - spk2;
        mem2 = m;
        spk2 = (m > 1.0f) ? 1.0f : 0.0f;
        const int t = (ch - 1) * FB_TC + tl;
        srec[(size_t)t * (B_ * NO_)] = spk2;
        mrec[(size_t)t * (B_ * NO_)] = m;
      }
    }

#pragma unroll
    for (int b = 0; b < 8; ++b) {
      const int rbase = bbyte + ((b * FB_TC + n15) * 65 + w * 8) * 4 + g;
      f32x4 acc = {0.0f, 0.0f, 0.0f, 0.0f};
#pragma unroll
      for (int kbl = 0; kbl < 8; ++kbl) {
        const unsigned byt = bytes[rbase + kbl * 4];
        const uint2 lo2 = lut2[byt & 15u];
        const uint2 hi2 = lut2[byt >> 4];
        const u32x4 A = {lo2.x, lo2.y, hi2.x, hi2.y};
        const short8 af = __builtin_bit_cast(short8, A);
        acc = __builtin_amdgcn_mfma_f32_16x16x32_bf16(
            af, __builtin_bit_cast(short8, bhi[kbl]), acc, 0, 0, 0);
        acc = __builtin_amdgcn_mfma_f32_16x16x32_bf16(
            af, __builtin_bit_cast(short8, blo[kbl]), acc, 0, 0, 0);
      }
      if (n15 < NO_)
        *reinterpret_cast<f32x4*>(
            &combC[w * 1280 + b * 160 + g * 40 + n15 * 4]) = acc;
      if (ch < FB_NCH - 1) {
        P1_STEP(bitsN, 2 * b);
        P1_STEP(bitsN, 2 * b + 1);
      }
    }

    __syncthreads();
  }

  if (lane < NO_) {
    const float* cbase =
        comb + ((FB_NCH - 1) & 1) * FB_COMB_PAR + w * 160 + lane * 4;
#pragma unroll
    for (int tl = 0; tl < FB_TC; ++tl) {
      const int off = (tl >> 2) * 40 + (tl & 3);
      float s = 0.0f;
#pragma unroll
      for (int ww = 0; ww < 8; ++ww) s += cbase[ww * 1280 + off];
      const float cur2 = s + b2v;
      float m = fmaf(0.95f, mem2, cur2);
      m = m - spk2;
      mem2 = m;
      spk2 = (m > 1.0f) ? 1.0f : 0.0f;
      const int t = (FB_NCH - 1) * FB_TC + tl;
      srec[(size_t)t * (B_ * NO_)] = spk2;
      mrec[(size_t)t * (B_ * NO_)] = m;
    }
  }
}

// ---------------------------------------------------------------------------
#define CUR1_BYTES ((size_t)B_ * NH_ * 4)            // 16 MB
#define BITS_BYTES ((size_t)B_ * T_ * 64 * 4)        // 67 MB
#define WS_NEED (CUR1_BYTES + BITS_BYTES)

extern "C" void kernel_launch(void* const* d_in, const int* in_sizes, int n_in,
                              void* d_out, int out_size, void* d_ws, size_t ws_size,
                              hipStream_t stream) {
  const float* x  = (const float*)d_in[0];
  const float* w1 = (const float*)d_in[1];
  const float* b1 = (const float*)d_in[2];
  const float* w2 = (const float*)d_in[3];
  const float* b2 = (const float*)d_in[4];
  float* out = (float*)d_out;
  float* cur1 = (float*)d_ws;

  float* spk2_rec = out;
  float* mem2_rec = out + (size_t)T_ * B_ * NO_;

  dim3 g1(NH_ / 128, B_ / 128);
  gemm_cur1<<<g1, 512, 0, stream>>>(x, w1, b1, cur1);

  if (ws_size >= WS_NEED) {
    unsigned* bitsg = (unsigned*)((char*)d_ws + CUR1_BYTES);
    spikegen<<<B_ / 4, 512, 0, stream>>>(cur1, (unsigned short*)bitsg);
    snn_out<<<B_ / 4, 512, 0, stream>>>(bitsg, w2, b2, spk2_rec, mem2_rec);
  } else {
    (void)hipFuncSetAttribute(reinterpret_cast<const void*>(snn_fused),
                              hipFuncAttributeMaxDynamicSharedMemorySize,
                              FB_SMEM);
    snn_fused<<<B_ / 8, 512, FB_SMEM, stream>>>(cur1, w2, b2, spk2_rec,
                                                mem2_rec);
  }
}

// Round 21
// 174.087 us; speedup vs baseline: 1.2028x; 1.1078x over previous
//
#include <hip/hip_runtime.h>
#include <hip/hip_bf16.h>

// SNN: B=2048, NI=1024, NH=2048, NO=10, T=128, BETA=0.95, THR=1.0
// r21: all kernels sized for the 64-VGPR tier (allocator spills anything
// 64..100 live down to 64 — observed r11/r17/r19/r20). K1 gemm per-tm
// A-frags (~60 live). A spikegen 8 neurons/lane (~42 live, byte bits).
// B snn_out unchanged (r20-verified). Fallback removed (ws >= 84MB proven).

#define B_   2048
#define NI_  1024
#define NH_  2048
#define NO_  10
#define T_   128

typedef __attribute__((ext_vector_type(8))) short short8;
typedef __attribute__((ext_vector_type(4))) float f32x4;
typedef __attribute__((ext_vector_type(4))) unsigned int u32x4;

__device__ __forceinline__ unsigned int bf16_rne(float f) {
  unsigned int u = __float_as_uint(f);
  return (u + 0x7FFFu + ((u >> 16) & 1u)) >> 16;
}

// ---------------- Kernel 1: cur1 = x @ w1^T + b1 (bf16x3 MFMA) --------------
#define G_ASTRIDE 144
#define G_AOFF    0
#define G_BOFF    (128 * G_ASTRIDE)
#define G_SMEM    (2 * 128 * G_ASTRIDE)

__global__ __launch_bounds__(512, 2) void gemm_cur1(
    const float* __restrict__ x, const float* __restrict__ w1,
    const float* __restrict__ b1, float* __restrict__ cur1) {
  __shared__ __align__(16) char smem[G_SMEM];
  const int tid = threadIdx.x;
  const int lane = tid & 63;
  const int wv = tid >> 6;
  const int wm = wv >> 2;
  const int wn = wv & 3;
  const int n15 = lane & 15;
  const int g = lane >> 4;
  const int brow = blockIdx.y * 128;
  const int bcol = blockIdx.x * 128;
  const int r_st = tid >> 3;
  const int kq = tid & 7;

  f32x4 acc[4][2];
#pragma unroll
  for (int tm = 0; tm < 4; ++tm)
#pragma unroll
    for (int tn = 0; tn < 2; ++tn) acc[tm][tn] = f32x4{0, 0, 0, 0};

  for (int kt = 0; kt < NI_; kt += 32) {
#pragma unroll
    for (int p = 0; p < 2; ++p) {
      const int r = r_st + p * 64;
      const float4 va = *reinterpret_cast<const float4*>(
          &x[(size_t)(brow + r) * NI_ + kt + kq * 4]);
      const float4 vb = *reinterpret_cast<const float4*>(
          &w1[(size_t)(bcol + r) * NI_ + kt + kq * 4]);
      const float fa[4] = {va.x, va.y, va.z, va.w};
      const float fb[4] = {vb.x, vb.y, vb.z, vb.w};
      unsigned ha[4], la[4], hb[4], lb[4];
#pragma unroll
      for (int c = 0; c < 4; ++c) {
        ha[c] = bf16_rne(fa[c]);
        la[c] = bf16_rne(fa[c] - __uint_as_float(ha[c] << 16));
        hb[c] = bf16_rne(fb[c]);
        lb[c] = bf16_rne(fb[c] - __uint_as_float(hb[c] << 16));
      }
      char* arow = smem + G_AOFF + r * G_ASTRIDE;
      char* brw  = smem + G_BOFF + r * G_ASTRIDE;
      *reinterpret_cast<uint2*>(arow + kq * 8) =
          uint2{ha[0] | (ha[1] << 16), ha[2] | (ha[3] << 16)};
      *reinterpret_cast<uint2*>(arow + 64 + kq * 8) =
          uint2{la[0] | (la[1] << 16), la[2] | (la[3] << 16)};
      *reinterpret_cast<uint2*>(brw + kq * 8) =
          uint2{hb[0] | (hb[1] << 16), hb[2] | (hb[3] << 16)};
      *reinterpret_cast<uint2*>(brw + 64 + kq * 8) =
          uint2{lb[0] | (lb[1] << 16), lb[2] | (lb[3] << 16)};
    }
    __syncthreads();

    // B-fragments (shared across tm)
    short8 bh2[2], bl2[2];
#pragma unroll
    for (int tn = 0; tn < 2; ++tn) {
      const char* p = smem + G_BOFF + (wn * 32 + tn * 16 + n15) * G_ASTRIDE;
      bh2[tn] = *reinterpret_cast<const short8*>(p + g * 16);
      bl2[tn] = *reinterpret_cast<const short8*>(p + 64 + g * 16);
    }
    // Per-tm A-fragments: caps concurrent liveness at ~60 regs (64-tier fit)
#pragma unroll
    for (int tm = 0; tm < 4; ++tm) {
      const char* p = smem + G_AOFF + (wm * 64 + tm * 16 + n15) * G_ASTRIDE;
      const short8 ah = *reinterpret_cast<const short8*>(p + g * 16);
      const short8 al = *reinterpret_cast<const short8*>(p + 64 + g * 16);
#pragma unroll
      for (int tn = 0; tn < 2; ++tn) {
        acc[tm][tn] = __builtin_amdgcn_mfma_f32_16x16x32_bf16(
            ah, bh2[tn], acc[tm][tn], 0, 0, 0);
        acc[tm][tn] = __builtin_amdgcn_mfma_f32_16x16x32_bf16(
            ah, bl2[tn], acc[tm][tn], 0, 0, 0);
        acc[tm][tn] = __builtin_amdgcn_mfma_f32_16x16x32_bf16(
            al, bh2[tn], acc[tm][tn], 0, 0, 0);
      }
    }
    __syncthreads();
  }

#pragma unroll
  for (int tn = 0; tn < 2; ++tn) {
    const int col = bcol + wn * 32 + tn * 16 + n15;
    const float bias = b1[col];
#pragma unroll
    for (int tm = 0; tm < 4; ++tm) {
      const int rowb = brow + wm * 64 + tm * 16 + g * 4;
#pragma unroll
      for (int r = 0; r < 4; ++r)
        cur1[(size_t)(rowb + r) * NH_ + col] = acc[tm][tn][r] + bias;
    }
  }
}

// ---------------- Kernel A: spikegen — layer-1 LIF -> bit-packed global -----
// 512 threads = 8 waves = 2 batches (bq=w>>2, qf=w&3); 8 neurons/lane.
// Byte b = qf*64+lane of the (b,t) 256-byte row covers neurons 8b..8b+7
// (bit j = neuron 8b+j) => word k covers 32k..32k+31, same layout as r20.
// Live state ~42 regs -> spill-free at the 64-VGPR tier, 8 waves/SIMD.
__global__ __launch_bounds__(512, 2) void spikegen(
    const float* __restrict__ cur1, unsigned char* __restrict__ bits8) {
  const int lane = threadIdx.x & 63;
  const int w = threadIdx.x >> 6;
  const int bq = w >> 2;
  const int qf = w & 3;
  const int bb = blockIdx.x * 2 + bq;

  float mem1[8], c1v[8], c1m[8], cc[8];
  {
    const float* base = cur1 + (size_t)bb * NH_ + qf * 512 + lane * 8;
#pragma unroll
    for (int q = 0; q < 2; ++q) {
      const float4 v = *reinterpret_cast<const float4*>(base + q * 4);
      c1v[q * 4 + 0] = v.x; c1v[q * 4 + 1] = v.y;
      c1v[q * 4 + 2] = v.z; c1v[q * 4 + 3] = v.w;
    }
#pragma unroll
    for (int i = 0; i < 8; ++i) {
      mem1[i] = 0.0f;
      c1m[i] = c1v[i] - 1.0f;
      cc[i] = c1v[i];
    }
  }

  unsigned char* dst = bits8 + (size_t)bb * T_ * 256 + qf * 64 + lane;
  for (int t = 0; t < T_; ++t) {
    unsigned W = 0;
#pragma unroll
    for (int i = 7; i >= 0; --i) {
      const float m = fmaf(0.95f, mem1[i], cc[i]);
      mem1[i] = m;
      const bool c = m > 1.0f;
      W = W + W + (c ? 1u : 0u);
      cc[i] = c ? c1m[i] : c1v[i];
    }
    dst[t * 256] = (unsigned char)W;
  }
}

// ---------------- Kernel B: snn_out — MFMA layer-2 + mem2 scan --------------
// (r20-verified, unchanged) 512 threads = 8 waves, 512 blocks (4 batches).
#define SO_TC 16

__global__ __launch_bounds__(512, 2) void snn_out(
    const unsigned* __restrict__ bitsg, const float* __restrict__ w2,
    const float* __restrict__ b2, float* __restrict__ spk2_rec,
    float* __restrict__ mem2_rec) {
  __shared__ uint2 lut[16];
  __shared__ __align__(16) unsigned bitsl[64 * 68];   // 17408 B
  __shared__ __align__(16) float comb[8 * 640];       // 20480 B
  const int tid = threadIdx.x;
  const int lane = tid & 63;
  const int w = tid >> 6;
  const int bbase = blockIdx.x * 4;

  if (tid < 16) {
    lut[tid] = uint2{(tid & 1 ? 0x3F80u : 0u) | (tid & 2 ? 0x3F800000u : 0u),
                     (tid & 4 ? 0x3F80u : 0u) | (tid & 8 ? 0x3F800000u : 0u)};
  }

  u32x4 bhi[8];
  {
    const int o = lane & 15;
    const int koff = (lane >> 4) * 8;
#pragma unroll
    for (int kbl = 0; kbl < 8; ++kbl) {
      const int kb = w * 8 + kbl;
      unsigned int hw[4];
#pragma unroll
      for (int p = 0; p < 4; ++p) {
        unsigned int h0 = 0, h1 = 0;
        if (o < NO_) {
          const int k = kb * 32 + koff + p * 2;
          h0 = bf16_rne(w2[(size_t)o * NH_ + k]);
          h1 = bf16_rne(w2[(size_t)o * NH_ + k + 1]);
        }
        hw[p] = h0 | (h1 << 16);
      }
      bhi[kbl] = u32x4{hw[0], hw[1], hw[2], hw[3]};
    }
  }

  float mem2 = 0.0f, spk2 = 0.0f, b2v = 0.0f;
  float *srec = nullptr, *mrec = nullptr;
  if (w < 4 && lane < NO_) {
    b2v = b2[lane];
    srec = spk2_rec + (size_t)(bbase + w) * NO_ + lane;
    mrec = mem2_rec + (size_t)(bbase + w) * NO_ + lane;
  }

  const int n15 = lane & 15;
  const int g = lane >> 4;
  const unsigned char* bytes = reinterpret_cast<const unsigned char*>(bitsl);

  for (int ch = 0; ch < T_ / SO_TC; ++ch) {
#pragma unroll
    for (int j = 0; j < 2; ++j) {
      const int q = tid + j * 512;
      const int row = q >> 4;
      const int kq = q & 15;
      const int b = row >> 4, tl = row & 15;
      const uint4 v = *reinterpret_cast<const uint4*>(
          bitsg + ((size_t)(bbase + b) * T_ + ch * SO_TC + tl) * 64 + kq * 4);
      *reinterpret_cast<uint4*>(bitsl + row * 68 + kq * 4) = v;
    }
    __syncthreads();

#pragma unroll
    for (int b = 0; b < 4; ++b) {
      const int rbase = ((b * SO_TC + n15) * 68 + w * 8) * 4 + g;
      f32x4 acc = {0.0f, 0.0f, 0.0f, 0.0f};
#pragma unroll
      for (int kbl = 0; kbl < 8; ++kbl) {
        const unsigned byt = bytes[rbase + kbl * 4];
        const uint2 lo2 = lut[byt & 15u];
        const uint2 hi2 = lut[byt >> 4];
        const u32x4 A = {lo2.x, lo2.y, hi2.x, hi2.y};
        const short8 af = __builtin_bit_cast(short8, A);
        acc = __builtin_amdgcn_mfma_f32_16x16x32_bf16(
            af, __builtin_bit_cast(short8, bhi[kbl]), acc, 0, 0, 0);
      }
      if (n15 < NO_)
        *reinterpret_cast<f32x4*>(
            &comb[w * 640 + b * 160 + g * 40 + n15 * 4]) = acc;
    }
    __syncthreads();

    if (w < 4 && lane < NO_) {
      const float* cbase = comb + w * 160 + lane * 4;
#pragma unroll
      for (int tl = 0; tl < SO_TC; ++tl) {
        const int off = (tl >> 2) * 40 + (tl & 3);
        float s = 0.0f;
#pragma unroll
        for (int kk = 0; kk < 8; ++kk) s += cbase[kk * 640 + off];
        const float cur2 = s + b2v;
        float m = fmaf(0.95f, mem2, cur2);
        m = m - spk2;
        mem2 = m;
        spk2 = (m > 1.0f) ? 1.0f : 0.0f;
        const int t = ch * SO_TC + tl;
        srec[(size_t)t * (B_ * NO_)] = spk2;
        mrec[(size_t)t * (B_ * NO_)] = m;
      }
    }
  }
}

// ---------------------------------------------------------------------------
#define CUR1_BYTES ((size_t)B_ * NH_ * 4)            // 16 MB
#define BITS_BYTES ((size_t)B_ * T_ * 64 * 4)        // 67 MB

extern "C" void kernel_launch(void* const* d_in, const int* in_sizes, int n_in,
                              void* d_out, int out_size, void* d_ws, size_t ws_size,
                              hipStream_t stream) {
  const float* x  = (const float*)d_in[0];
  const float* w1 = (const float*)d_in[1];
  const float* b1 = (const float*)d_in[2];
  const float* w2 = (const float*)d_in[3];
  const float* b2 = (const float*)d_in[4];
  float* out = (float*)d_out;
  float* cur1 = (float*)d_ws;
  unsigned* bitsg = (unsigned*)((char*)d_ws + CUR1_BYTES);

  float* spk2_rec = out;
  float* mem2_rec = out + (size_t)T_ * B_ * NO_;

  dim3 g1(NH_ / 128, B_ / 128);
  gemm_cur1<<<g1, 512, 0, stream>>>(x, w1, b1, cur1);
  spikegen<<<B_ / 2, 512, 0, stream>>>(cur1, (unsigned char*)bitsg);
  snn_out<<<B_ / 4, 512, 0, stream>>>(bitsg, w2, b2, spk2_rec, mem2_rec);
}

// Round 22
// 170.827 us; speedup vs baseline: 1.2258x; 1.0191x over previous
//
#include <hip/hip_runtime.h>
#include <hip/hip_bf16.h>

// SNN: B=2048, NI=1024, NH=2048, NO=10, T=128, BETA=0.95, THR=1.0
// r22: spikegen bit-accumulate via float fma (Wf = 2*Wf + s, s = cndmask
// 1.0/0) — 5 simple VALU/neuron-step vs the ~9.5 the integer addc idiom
// compiled to (r21 PMC). (512,4): live ~38 regs fits the 64-cap spill-free.
// gemm (r21 per-tm A-frags) and snn_out (r20) frozen.

#define B_   2048
#define NI_  1024
#define NH_  2048
#define NO_  10
#define T_   128

typedef __attribute__((ext_vector_type(8))) short short8;
typedef __attribute__((ext_vector_type(4))) float f32x4;
typedef __attribute__((ext_vector_type(4))) unsigned int u32x4;

__device__ __forceinline__ unsigned int bf16_rne(float f) {
  unsigned int u = __float_as_uint(f);
  return (u + 0x7FFFu + ((u >> 16) & 1u)) >> 16;
}

// ---------------- Kernel 1: cur1 = x @ w1^T + b1 (bf16x3 MFMA) --------------
#define G_ASTRIDE 144
#define G_AOFF    0
#define G_BOFF    (128 * G_ASTRIDE)
#define G_SMEM    (2 * 128 * G_ASTRIDE)

__global__ __launch_bounds__(512, 2) void gemm_cur1(
    const float* __restrict__ x, const float* __restrict__ w1,
    const float* __restrict__ b1, float* __restrict__ cur1) {
  __shared__ __align__(16) char smem[G_SMEM];
  const int tid = threadIdx.x;
  const int lane = tid & 63;
  const int wv = tid >> 6;
  const int wm = wv >> 2;
  const int wn = wv & 3;
  const int n15 = lane & 15;
  const int g = lane >> 4;
  const int brow = blockIdx.y * 128;
  const int bcol = blockIdx.x * 128;
  const int r_st = tid >> 3;
  const int kq = tid & 7;

  f32x4 acc[4][2];
#pragma unroll
  for (int tm = 0; tm < 4; ++tm)
#pragma unroll
    for (int tn = 0; tn < 2; ++tn) acc[tm][tn] = f32x4{0, 0, 0, 0};

  for (int kt = 0; kt < NI_; kt += 32) {
#pragma unroll
    for (int p = 0; p < 2; ++p) {
      const int r = r_st + p * 64;
      const float4 va = *reinterpret_cast<const float4*>(
          &x[(size_t)(brow + r) * NI_ + kt + kq * 4]);
      const float4 vb = *reinterpret_cast<const float4*>(
          &w1[(size_t)(bcol + r) * NI_ + kt + kq * 4]);
      const float fa[4] = {va.x, va.y, va.z, va.w};
      const float fb[4] = {vb.x, vb.y, vb.z, vb.w};
      unsigned ha[4], la[4], hb[4], lb[4];
#pragma unroll
      for (int c = 0; c < 4; ++c) {
        ha[c] = bf16_rne(fa[c]);
        la[c] = bf16_rne(fa[c] - __uint_as_float(ha[c] << 16));
        hb[c] = bf16_rne(fb[c]);
        lb[c] = bf16_rne(fb[c] - __uint_as_float(hb[c] << 16));
      }
      char* arow = smem + G_AOFF + r * G_ASTRIDE;
      char* brw  = smem + G_BOFF + r * G_ASTRIDE;
      *reinterpret_cast<uint2*>(arow + kq * 8) =
          uint2{ha[0] | (ha[1] << 16), ha[2] | (ha[3] << 16)};
      *reinterpret_cast<uint2*>(arow + 64 + kq * 8) =
          uint2{la[0] | (la[1] << 16), la[2] | (la[3] << 16)};
      *reinterpret_cast<uint2*>(brw + kq * 8) =
          uint2{hb[0] | (hb[1] << 16), hb[2] | (hb[3] << 16)};
      *reinterpret_cast<uint2*>(brw + 64 + kq * 8) =
          uint2{lb[0] | (lb[1] << 16), lb[2] | (lb[3] << 16)};
    }
    __syncthreads();

    short8 bh2[2], bl2[2];
#pragma unroll
    for (int tn = 0; tn < 2; ++tn) {
      const char* p = smem + G_BOFF + (wn * 32 + tn * 16 + n15) * G_ASTRIDE;
      bh2[tn] = *reinterpret_cast<const short8*>(p + g * 16);
      bl2[tn] = *reinterpret_cast<const short8*>(p + 64 + g * 16);
    }
#pragma unroll
    for (int tm = 0; tm < 4; ++tm) {
      const char* p = smem + G_AOFF + (wm * 64 + tm * 16 + n15) * G_ASTRIDE;
      const short8 ah = *reinterpret_cast<const short8*>(p + g * 16);
      const short8 al = *reinterpret_cast<const short8*>(p + 64 + g * 16);
#pragma unroll
      for (int tn = 0; tn < 2; ++tn) {
        acc[tm][tn] = __builtin_amdgcn_mfma_f32_16x16x32_bf16(
            ah, bh2[tn], acc[tm][tn], 0, 0, 0);
        acc[tm][tn] = __builtin_amdgcn_mfma_f32_16x16x32_bf16(
            ah, bl2[tn], acc[tm][tn], 0, 0, 0);
        acc[tm][tn] = __builtin_amdgcn_mfma_f32_16x16x32_bf16(
            al, bh2[tn], acc[tm][tn], 0, 0, 0);
      }
    }
    __syncthreads();
  }

#pragma unroll
  for (int tn = 0; tn < 2; ++tn) {
    const int col = bcol + wn * 32 + tn * 16 + n15;
    const float bias = b1[col];
#pragma unroll
    for (int tm = 0; tm < 4; ++tm) {
      const int rowb = brow + wm * 64 + tm * 16 + g * 4;
#pragma unroll
      for (int r = 0; r < 4; ++r)
        cur1[(size_t)(rowb + r) * NH_ + col] = acc[tm][tn][r] + bias;
    }
  }
}

// ---------------- Kernel A: spikegen — layer-1 LIF -> bit-packed global -----
// 512 threads = 8 waves = 2 batches (bq=w>>2, qf=w&3); 8 neurons/lane.
// Byte b = qf*64+lane of the (b,t) 256-byte row covers neurons 8b..8b+7
// (bit j = neuron 8b+j) — layout identical to r21.
// Bit word accumulated in FLOAT: Wf = 2*Wf + s, s = cndmask(0,1.0) — 5
// simple VALU/neuron-step; exact for 8 bits (Wf <= 255).
__global__ __launch_bounds__(512, 4) void spikegen(
    const float* __restrict__ cur1, unsigned char* __restrict__ bits8) {
  const int lane = threadIdx.x & 63;
  const int w = threadIdx.x >> 6;
  const int bq = w >> 2;
  const int qf = w & 3;
  const int bb = blockIdx.x * 2 + bq;

  float mem1[8], c1v[8], c1m[8], cc[8];
  {
    const float* base = cur1 + (size_t)bb * NH_ + qf * 512 + lane * 8;
#pragma unroll
    for (int q = 0; q < 2; ++q) {
      const float4 v = *reinterpret_cast<const float4*>(base + q * 4);
      c1v[q * 4 + 0] = v.x; c1v[q * 4 + 1] = v.y;
      c1v[q * 4 + 2] = v.z; c1v[q * 4 + 3] = v.w;
    }
#pragma unroll
    for (int i = 0; i < 8; ++i) {
      mem1[i] = 0.0f;
      c1m[i] = c1v[i] - 1.0f;
      cc[i] = c1v[i];
    }
  }

  const float vone = 1.0f;  // VGPR-resident 1.0 for cndmask
  unsigned char* dst = bits8 + (size_t)bb * T_ * 256 + qf * 64 + lane;
  for (int t = 0; t < T_; ++t) {
    float Wf = 0.0f;
#pragma unroll
    for (int i = 7; i >= 0; --i) {
      const float m = fmaf(0.95f, mem1[i], cc[i]);
      mem1[i] = m;
      const bool c = m > 1.0f;
      const float s = c ? vone : 0.0f;     // v_cndmask
      Wf = fmaf(2.0f, Wf, s);              // v_fma, 2.0 inline const
      cc[i] = c ? c1m[i] : c1v[i];         // v_cndmask (same vcc)
    }
    dst[t * 256] = (unsigned char)(unsigned)Wf;
  }
}

// ---------------- Kernel B: snn_out — MFMA layer-2 + mem2 scan --------------
// (r20-verified, unchanged) 512 threads = 8 waves, 512 blocks (4 batches).
#define SO_TC 16

__global__ __launch_bounds__(512, 2) void snn_out(
    const unsigned* __restrict__ bitsg, const float* __restrict__ w2,
    const float* __restrict__ b2, float* __restrict__ spk2_rec,
    float* __restrict__ mem2_rec) {
  __shared__ uint2 lut[16];
  __shared__ __align__(16) unsigned bitsl[64 * 68];   // 17408 B
  __shared__ __align__(16) float comb[8 * 640];       // 20480 B
  const int tid = threadIdx.x;
  const int lane = tid & 63;
  const int w = tid >> 6;
  const int bbase = blockIdx.x * 4;

  if (tid < 16) {
    lut[tid] = uint2{(tid & 1 ? 0x3F80u : 0u) | (tid & 2 ? 0x3F800000u : 0u),
                     (tid & 4 ? 0x3F80u : 0u) | (tid & 8 ? 0x3F800000u : 0u)};
  }

  u32x4 bhi[8];
  {
    const int o = lane & 15;
    const int koff = (lane >> 4) * 8;
#pragma unroll
    for (int kbl = 0; kbl < 8; ++kbl) {
      const int kb = w * 8 + kbl;
      unsigned int hw[4];
#pragma unroll
      for (int p = 0; p < 4; ++p) {
        unsigned int h0 = 0, h1 = 0;
        if (o < NO_) {
          const int k = kb * 32 + koff + p * 2;
          h0 = bf16_rne(w2[(size_t)o * NH_ + k]);
          h1 = bf16_rne(w2[(size_t)o * NH_ + k + 1]);
        }
        hw[p] = h0 | (h1 << 16);
      }
      bhi[kbl] = u32x4{hw[0], hw[1], hw[2], hw[3]};
    }
  }

  float mem2 = 0.0f, spk2 = 0.0f, b2v = 0.0f;
  float *srec = nullptr, *mrec = nullptr;
  if (w < 4 && lane < NO_) {
    b2v = b2[lane];
    srec = spk2_rec + (size_t)(bbase + w) * NO_ + lane;
    mrec = mem2_rec + (size_t)(bbase + w) * NO_ + lane;
  }

  const int n15 = lane & 15;
  const int g = lane >> 4;
  const unsigned char* bytes = reinterpret_cast<const unsigned char*>(bitsl);

  for (int ch = 0; ch < T_ / SO_TC; ++ch) {
#pragma unroll
    for (int j = 0; j < 2; ++j) {
      const int q = tid + j * 512;
      const int row = q >> 4;
      const int kq = q & 15;
      const int b = row >> 4, tl = row & 15;
      const uint4 v = *reinterpret_cast<const uint4*>(
          bitsg + ((size_t)(bbase + b) * T_ + ch * SO_TC + tl) * 64 + kq * 4);
      *reinterpret_cast<uint4*>(bitsl + row * 68 + kq * 4) = v;
    }
    __syncthreads();

#pragma unroll
    for (int b = 0; b < 4; ++b) {
      const int rbase = ((b * SO_TC + n15) * 68 + w * 8) * 4 + g;
      f32x4 acc = {0.0f, 0.0f, 0.0f, 0.0f};
#pragma unroll
      for (int kbl = 0; kbl < 8; ++kbl) {
        const unsigned byt = bytes[rbase + kbl * 4];
        const uint2 lo2 = lut[byt & 15u];
        const uint2 hi2 = lut[byt >> 4];
        const u32x4 A = {lo2.x, lo2.y, hi2.x, hi2.y};
        const short8 af = __builtin_bit_cast(short8, A);
        acc = __builtin_amdgcn_mfma_f32_16x16x32_bf16(
            af, __builtin_bit_cast(short8, bhi[kbl]), acc, 0, 0, 0);
      }
      if (n15 < NO_)
        *reinterpret_cast<f32x4*>(
            &comb[w * 640 + b * 160 + g * 40 + n15 * 4]) = acc;
    }
    __syncthreads();

    if (w < 4 && lane < NO_) {
      const float* cbase = comb + w * 160 + lane * 4;
#pragma unroll
      for (int tl = 0; tl < SO_TC; ++tl) {
        const int off = (tl >> 2) * 40 + (tl & 3);
        float s = 0.0f;
#pragma unroll
        for (int kk = 0; kk < 8; ++kk) s += cbase[kk * 640 + off];
        const float cur2 = s + b2v;
        float m = fmaf(0.95f, mem2, cur2);
        m = m - spk2;
        mem2 = m;
        spk2 = (m > 1.0f) ? 1.0f : 0.0f;
        const int t = ch * SO_TC + tl;
        srec[(size_t)t * (B_ * NO_)] = spk2;
        mrec[(size_t)t * (B_ * NO_)] = m;
      }
    }
  }
}

// ---------------------------------------------------------------------------
#define CUR1_BYTES ((size_t)B_ * NH_ * 4)            // 16 MB
#define BITS_BYTES ((size_t)B_ * T_ * 64 * 4)        // 67 MB

extern "C" void kernel_launch(void* const* d_in, const int* in_sizes, int n_in,
                              void* d_out, int out_size, void* d_ws, size_t ws_size,
                              hipStream_t stream) {
  const float* x  = (const float*)d_in[0];
  const float* w1 = (const float*)d_in[1];
  const float* b1 = (const float*)d_in[2];
  const float* w2 = (const float*)d_in[3];
  const float* b2 = (const float*)d_in[4];
  float* out = (float*)d_out;
  float* cur1 = (float*)d_ws;
  unsigned* bitsg = (unsigned*)((char*)d_ws + CUR1_BYTES);

  float* spk2_rec = out;
  float* mem2_rec = out + (size_t)T_ * B_ * NO_;

  dim3 g1(NH_ / 128, B_ / 128);
  gemm_cur1<<<g1, 512, 0, stream>>>(x, w1, b1, cur1);
  spikegen<<<B_ / 2, 512, 0, stream>>>(cur1, (unsigned char*)bitsg);
  snn_out<<<B_ / 4, 512, 0, stream>>>(bitsg, w2, b2, spk2_rec, mem2_rec);
}